// Round 13
// baseline (229.901 us; speedup 1.0000x reference)
//
#include <hip/hip_runtime.h>
#include <hip/hip_fp16.h>

#define S_LEN 512
#define B_DIM 1024
#define T_DIM 48
#define L2E 1.4426950408889634f
#define LN2 0.6931471805599453f

// v_exp_f32 computes 2^x ; v_log_f32 computes log2(x)
#define EXP2F(x) __builtin_amdgcn_exp2f(x)
#define LOG2F(x) __builtin_amdgcn_logf(x)

typedef _Float16 h2v __attribute__((ext_vector_type(2)));

// packed f16 max (ROCm 7.2 lacks __hmax2): <2 x half> llvm.maxnum -> v_pk_max_f16
__device__ __forceinline__ __half2 hmax2(__half2 a, __half2 b) {
  h2v r = __builtin_elementwise_max(__builtin_bit_cast(h2v, a),
                                    __builtin_bit_cast(h2v, b));
  return __builtin_bit_cast(__half2, r);
}

// broadcast the 32-bit pair held by `lane` to all lanes (readlane -> SGPR)
__device__ __forceinline__ __half2 bpick(__half2 src, int lane) {
  int s = __builtin_amdgcn_readlane(__builtin_bit_cast(int, src), lane);
  return __builtin_bit_cast(__half2, s);
}

// ---- DPP wave-64 reduction helpers (full result valid in lane 63) ----
template <int CTRL, int RMASK>
__device__ __forceinline__ float dppmovf(float v) {
  return __int_as_float(__builtin_amdgcn_update_dpp(
      __float_as_int(v), __float_as_int(v), CTRL, RMASK, 0xF, false));
}
template <int CTRL, int RMASK>
__device__ __forceinline__ float dppmaxf(float m) {
  return fmaxf(m, dppmovf<CTRL, RMASK>(m));
}
template <int CTRL, int RMASK>
__device__ __forceinline__ float dppaddf(float m) {
  return m + dppmovf<CTRL, RMASK>(m);
}

__device__ __forceinline__ float wave_max63(float m) {
  m = dppmaxf<0xB1, 0xF>(m);   // xor 1
  m = dppmaxf<0x4E, 0xF>(m);   // xor 2
  m = dppmaxf<0x141, 0xF>(m);  // xor 4 (row_half_mirror)
  m = dppmaxf<0x140, 0xF>(m);  // xor 8 (row_mirror)
  m = dppmaxf<0x142, 0xA>(m);  // row_bcast15 -> rows 1,3
  m = dppmaxf<0x143, 0xC>(m);  // row_bcast31 -> rows 2,3 ; lane63 = full max
  return __int_as_float(__builtin_amdgcn_readlane(__float_as_int(m), 63));
}
__device__ __forceinline__ float wave_sum63(float m) {
  m = dppaddf<0xB1, 0xF>(m);
  m = dppaddf<0x4E, 0xF>(m);
  m = dppaddf<0x141, 0xF>(m);
  m = dppaddf<0x140, 0xF>(m);
  m = dppaddf<0x142, 0xA>(m);
  m = dppaddf<0x143, 0xC>(m);
  return __int_as_float(__builtin_amdgcn_readlane(__float_as_int(m), 63));
}

// ---- main scan: blocks 0..1023 = forward(LSE) chain, 1024..2047 = viterbi(max).
// One wave per chain; lane = tag index, lanes >= 48 clone lane 47.
// __launch_bounds__(64, 2): grid limits us to 2 waves/SIMD anyway, so let the
// register allocator use up to ~128 VGPRs -- keeps Epk/Tpk resident instead of
// spilling/rematerializing them every step (r12 showed VGPR_Count=32 with a
// static need of ~45+, i.e. per-step scratch traffic).
__global__ __launch_bounds__(64, 2)
void crf_scan(const float* __restrict__ em, const float* __restrict__ mask,
              const float* __restrict__ trans, const float* __restrict__ startT,
              const float* __restrict__ stopT, float* __restrict__ out)
{
  const int b    = blockIdx.x & (B_DIM - 1);
  const int mode = blockIdx.x >> 10;   // 0 = fv, 1 = vv
  const int i    = threadIdx.x;
  const int ri   = (i < T_DIM) ? i : (T_DIM - 1);

  float v = startT[ri] + em[(size_t)b * T_DIM + ri];

  const float* emb = em + (size_t)b * T_DIM + ri;
  const size_t estep = (size_t)B_DIM * T_DIM;
  float e1 = emb[1 * estep];
  float e2 = emb[2 * estep];
  float e3 = emb[3 * estep];
  float mk = mask[B_DIM + b];

  if (mode == 0) {
    // per-lane row ri of exp(trans), f16 RNE packed over j-pairs
    __half2 Epk[24];
#pragma unroll
    for (int k = 0; k < 24; ++k)
      Epk[k] = __floats2half2_rn(EXP2F(trans[ri * T_DIM + 2 * k]     * L2E),
                                 EXP2F(trans[ri * T_DIM + 2 * k + 1] * L2E));

    for (int s = 1; s < S_LEN; ++s) {
      int sp = (s + 3 < S_LEN) ? s + 3 : S_LEN - 1;
      float ep  = emb[(size_t)sp * estep];
      int sn = (s + 1 < S_LEN) ? s + 1 : S_LEN - 1;
      float mkn = mask[sn * B_DIM + b];

      float mf = wave_max63(v);                      // exp stability (p <= 1)
      float p  = EXP2F((v - mf) * L2E);
      float pn = dppmovf<0xB1, 0xF>(p);              // neighbor (i^1)
      __half2 pp = __floats2half2_rn(p, pn);         // even lane 2k: (p_2k, p_2k+1)

      __half2 a0 = __float2half2_rn(0.f), a1 = a0, a2 = a0, a3 = a0;
#pragma unroll
      for (int g = 0; g < 4; ++g) {
        // batch of 6 broadcasts -> 6 live SGPRs -> hazards overlap
        __half2 t0 = bpick(pp, 12 * g + 0);
        __half2 t1 = bpick(pp, 12 * g + 2);
        __half2 t2 = bpick(pp, 12 * g + 4);
        __half2 t3 = bpick(pp, 12 * g + 6);
        __half2 t4 = bpick(pp, 12 * g + 8);
        __half2 t5 = bpick(pp, 12 * g + 10);
        a0 = __hfma2(t0, Epk[6 * g + 0], a0);
        a1 = __hfma2(t1, Epk[6 * g + 1], a1);
        a2 = __hfma2(t2, Epk[6 * g + 2], a2);
        a3 = __hfma2(t3, Epk[6 * g + 3], a3);
        a0 = __hfma2(t4, Epk[6 * g + 4], a0);
        a1 = __hfma2(t5, Epk[6 * g + 5], a1);
      }
      a0 = __hadd2(a0, a1); a2 = __hadd2(a2, a3); a0 = __hadd2(a0, a2);
      float accF = __low2float(a0) + __high2float(a0);  // sum_j p_j*exp(t_ij)

      // new_fv = em + mf + ln(accF), absolute coordinates
      float fnew = fmaf(LN2, LOG2F(fmaxf(accF, 1e-30f)), e1 + mf);
      v = fmaf(mk, fnew - v, v);                     // mask blend

      e1 = e2; e2 = e3; e3 = ep; mk = mkn;
    }
    float q  = v + stopT[ri];
    float mq = wave_max63(q);
    float e  = EXP2F((q - mq) * L2E);
    e = (i < T_DIM) ? e : 0.f;                       // zero clone lanes
    float alpha = mq + LN2 * LOG2F(wave_sum63(e));
    if (i == 0) out[1 + B_DIM + b] = alpha;
  } else {
    __half2 Tpk[24];
#pragma unroll
    for (int k = 0; k < 24; ++k)
      Tpk[k] = __floats2half2_rn(trans[ri * T_DIM + 2 * k],
                                 trans[ri * T_DIM + 2 * k + 1]);

    // stale-max rebase: exact wave max every 8 steps (passed at absmax 8)
    float m_ref = wave_max63(v);
    const __half2 NEG = __floats2half2_rn(-60000.f, -60000.f);

#pragma unroll 8
    for (int s = 1; s < S_LEN; ++s) {
      int sp = (s + 3 < S_LEN) ? s + 3 : S_LEN - 1;
      float ep  = emb[(size_t)sp * estep];
      int sn = (s + 1 < S_LEN) ? s + 1 : S_LEN - 1;
      float mkn = mask[sn * B_DIM + b];

      if ((s & 7) == 0) m_ref = wave_max63(v);       // compile-time per unroll pos
      float vr = v - m_ref;                          // f16-safe magnitude
      float vn_ = dppmovf<0xB1, 0xF>(vr);
      __half2 vp = __floats2half2_rn(vr, vn_);       // even lane 2k: (vr_2k, vr_2k+1)

      __half2 m0 = NEG, m1 = NEG, m2 = NEG, m3 = NEG;
#pragma unroll
      for (int g = 0; g < 4; ++g) {
        __half2 t0 = bpick(vp, 12 * g + 0);
        __half2 t1 = bpick(vp, 12 * g + 2);
        __half2 t2 = bpick(vp, 12 * g + 4);
        __half2 t3 = bpick(vp, 12 * g + 6);
        __half2 t4 = bpick(vp, 12 * g + 8);
        __half2 t5 = bpick(vp, 12 * g + 10);
        m0 = hmax2(m0, __hadd2(t0, Tpk[6 * g + 0]));
        m1 = hmax2(m1, __hadd2(t1, Tpk[6 * g + 1]));
        m2 = hmax2(m2, __hadd2(t2, Tpk[6 * g + 2]));
        m3 = hmax2(m3, __hadd2(t3, Tpk[6 * g + 3]));
        m0 = hmax2(m0, __hadd2(t4, Tpk[6 * g + 4]));
        m1 = hmax2(m1, __hadd2(t5, Tpk[6 * g + 5]));
      }
      m0 = hmax2(hmax2(m0, m1), hmax2(m2, m3));
      float mx = fmaxf(__low2float(m0), __high2float(m0));  // max_j(vr_j+t_ij)

      float vnew = e1 + m_ref + mx;                  // back to absolute coords
      v = fmaf(mk, vnew - v, v);                     // mask blend

      e1 = e2; e2 = e3; e3 = ep; mk = mkn;
    }
    float best = wave_max63(v + stopT[ri]);
    if (i == 0) out[1 + 2 * B_DIM + b] = best;
  }
}

// ---- real-path score: one block per b, deterministic LDS tree reduction ----
__global__ __launch_bounds__(256)
void crf_real(const float* __restrict__ em, const int* __restrict__ tags,
              const float* __restrict__ mask, const float* __restrict__ trans,
              const float* __restrict__ startT, const float* __restrict__ stopT,
              float* __restrict__ out)
{
  __shared__ float red[256];
  const int b = blockIdx.x;
  const int t = threadIdx.x;
  float acc = 0.f;
  for (int s = 1 + t; s < S_LEN; s += 256) {
    int   tp  = tags[(s - 1) * B_DIM + b];
    int   tc  = tags[s * B_DIM + b];
    float mkv = mask[s * B_DIM + b];
    float emt = em[((size_t)s * B_DIM + b) * T_DIM + tc];
    acc = fmaf(mkv, trans[tp * T_DIM + tc] + emt, acc);
  }
  red[t] = acc;
  __syncthreads();
  for (int w = 128; w > 0; w >>= 1) {
    if (t < w) red[t] += red[t + w];
    __syncthreads();
  }
  if (t == 0)
    out[1 + b] = startT[tags[b]] + stopT[tags[(S_LEN - 1) * B_DIM + b]] + red[0];
}

// ---- loss = mean(alpha - real) ----
__global__ __launch_bounds__(256)
void crf_loss(float* __restrict__ out)
{
  __shared__ float red[256];
  int t = threadIdx.x;
  float a = 0.f;
  for (int b = t; b < B_DIM; b += 256)
    a += out[1 + B_DIM + b] - out[1 + b];
  red[t] = a;
  __syncthreads();
  for (int w = 128; w > 0; w >>= 1) {
    if (t < w) red[t] += red[t + w];
    __syncthreads();
  }
  if (t == 0) out[0] = red[0] * (1.0f / B_DIM);
}

extern "C" void kernel_launch(void* const* d_in, const int* in_sizes, int n_in,
                              void* d_out, int out_size, void* d_ws, size_t ws_size,
                              hipStream_t stream) {
  (void)in_sizes; (void)n_in; (void)d_ws; (void)ws_size; (void)out_size;
  const float* em     = (const float*)d_in[0];
  const int*   tags   = (const int*)d_in[1];
  const float* mask   = (const float*)d_in[2];
  const float* trans  = (const float*)d_in[3];
  const float* startT = (const float*)d_in[4];
  const float* stopT  = (const float*)d_in[5];
  float* out = (float*)d_out;

  hipLaunchKernelGGL(crf_scan, dim3(2 * B_DIM), dim3(64), 0, stream,
                     em, mask, trans, startT, stopT, out);
  hipLaunchKernelGGL(crf_real, dim3(B_DIM), dim3(256), 0, stream,
                     em, tags, mask, trans, startT, stopT, out);
  hipLaunchKernelGGL(crf_loss, dim3(1), dim3(256), 0, stream, out);
}

// Round 14
// 224.106 us; speedup vs baseline: 1.0259x; 1.0259x over previous
//
#include <hip/hip_runtime.h>
#include <hip/hip_fp16.h>

#define S_LEN 512
#define B_DIM 1024
#define T_DIM 48
#define L2E 1.4426950408889634f
#define LN2 0.6931471805599453f

// v_exp_f32 computes 2^x ; v_log_f32 computes log2(x)
#define EXP2F(x) __builtin_amdgcn_exp2f(x)
#define LOG2F(x) __builtin_amdgcn_logf(x)

typedef _Float16 h2v __attribute__((ext_vector_type(2)));

// packed f16 max (ROCm 7.2 lacks __hmax2)
__device__ __forceinline__ __half2 hmax2(__half2 a, __half2 b) {
  h2v r = __builtin_elementwise_max(__builtin_bit_cast(h2v, a),
                                    __builtin_bit_cast(h2v, b));
  return __builtin_bit_cast(__half2, r);
}

// broadcast the 32-bit pair held by `lane` to all lanes (readlane -> SGPR)
__device__ __forceinline__ __half2 bpick(__half2 src, int lane) {
  int s = __builtin_amdgcn_readlane(__builtin_bit_cast(int, src), lane);
  return __builtin_bit_cast(__half2, s);
}

// ---- DPP wave-64 reduction helpers (full result valid in lane 63) ----
template <int CTRL, int RMASK>
__device__ __forceinline__ float dppmovf(float v) {
  return __int_as_float(__builtin_amdgcn_update_dpp(
      __float_as_int(v), __float_as_int(v), CTRL, RMASK, 0xF, false));
}
template <int CTRL, int RMASK>
__device__ __forceinline__ float dppmaxf(float m) {
  return fmaxf(m, dppmovf<CTRL, RMASK>(m));
}
template <int CTRL, int RMASK>
__device__ __forceinline__ float dppaddf(float m) {
  return m + dppmovf<CTRL, RMASK>(m);
}

__device__ __forceinline__ float wave_max63(float m) {
  m = dppmaxf<0xB1, 0xF>(m);   // xor 1
  m = dppmaxf<0x4E, 0xF>(m);   // xor 2
  m = dppmaxf<0x141, 0xF>(m);  // xor 4
  m = dppmaxf<0x140, 0xF>(m);  // xor 8
  m = dppmaxf<0x142, 0xA>(m);  // row_bcast15
  m = dppmaxf<0x143, 0xC>(m);  // row_bcast31 ; lane63 = full max
  return __int_as_float(__builtin_amdgcn_readlane(__float_as_int(m), 63));
}
__device__ __forceinline__ float wave_sum63(float m) {
  m = dppaddf<0xB1, 0xF>(m);
  m = dppaddf<0x4E, 0xF>(m);
  m = dppaddf<0x141, 0xF>(m);
  m = dppaddf<0x140, 0xF>(m);
  m = dppaddf<0x142, 0xA>(m);
  m = dppaddf<0x143, 0xC>(m);
  return __int_as_float(__builtin_amdgcn_readlane(__float_as_int(m), 63));
}

// Fused kernel, 64 threads/block:
//   blocks [0, 1024)      : real-path gather score (wave reduction, no LDS)
//   blocks [1024, 2048)   : forward (LSE) chains, exp-domain state
//   blocks [2048, 3072)   : viterbi (max) chains, stale-max-8 rebase
// E/T fragments as 24 NAMED __half2 registers (arrays were demoted to
// scratch: r12/r13 showed VGPR_Count 32-40 < static need and +64MB FETCH).
__global__ __launch_bounds__(64, 2)
void crf_fused(const float* __restrict__ em, const int* __restrict__ tags,
               const float* __restrict__ mask, const float* __restrict__ trans,
               const float* __restrict__ startT, const float* __restrict__ stopT,
               float* __restrict__ out)
{
  const int blk = blockIdx.x;
  const int i   = threadIdx.x;

  if (blk < B_DIM) {                       // ---- real-path score ----
    const int b = blk;
    float acc = 0.f;
#pragma unroll
    for (int k = 0; k < 8; ++k) {
      int s = 1 + i + (k << 6);
      if (s < S_LEN) {
        int   tp  = tags[(s - 1) * B_DIM + b];
        int   tc  = tags[s * B_DIM + b];
        float mkv = mask[s * B_DIM + b];
        float emt = em[((size_t)s * B_DIM + b) * T_DIM + tc];
        acc = fmaf(mkv, trans[tp * T_DIM + tc] + emt, acc);
      }
    }
    float tot = wave_sum63(acc);
    if (i == 0)
      out[1 + b] = startT[tags[b]] + stopT[tags[(S_LEN - 1) * B_DIM + b]] + tot;
    return;
  }

  const int idx  = blk - B_DIM;
  const int b    = idx & (B_DIM - 1);
  const int mode = idx >> 10;              // 0 = fv, 1 = vv (same-XCD pairing)
  const int ri   = (i < T_DIM) ? i : (T_DIM - 1);

  const float* emb = em + (size_t)b * T_DIM + ri;
  const size_t estep = (size_t)B_DIM * T_DIM;
  float e1 = emb[1 * estep], e2 = emb[2 * estep], e3 = emb[3 * estep];
  float mk = mask[B_DIM + b];
  const float* pf  = emb + 4 * estep;      // prefetch ptr (row s+3)
  const float* pmk = mask + 2 * B_DIM + b; // mask prefetch (row s+1)

  if (mode == 0) {
    // ---- forward chain, exp-domain state: fv = LN2*k2 + ln(p) ----
#define DECL_E(n) __half2 E##n = __floats2half2_rn( \
      EXP2F(trans[ri * T_DIM + 2*(n)    ] * L2E),   \
      EXP2F(trans[ri * T_DIM + 2*(n) + 1] * L2E));
    DECL_E(0)  DECL_E(1)  DECL_E(2)  DECL_E(3)  DECL_E(4)  DECL_E(5)
    DECL_E(6)  DECL_E(7)  DECL_E(8)  DECL_E(9)  DECL_E(10) DECL_E(11)
    DECL_E(12) DECL_E(13) DECL_E(14) DECL_E(15) DECL_E(16) DECL_E(17)
    DECL_E(18) DECL_E(19) DECL_E(20) DECL_E(21) DECL_E(22) DECL_E(23)

    float p  = EXP2F((startT[ri] + emb[0]) * L2E);   // |fv0| <= ~9, f32 safe
    float k2 = 0.f;

#define FVG(g, Ea, Eb, Ec, Ed, Ee, Ef)                 \
    { __half2 t0 = bpick(pp, 12*(g) + 0);              \
      __half2 t1 = bpick(pp, 12*(g) + 2);              \
      __half2 t2 = bpick(pp, 12*(g) + 4);              \
      __half2 t3 = bpick(pp, 12*(g) + 6);              \
      __half2 t4 = bpick(pp, 12*(g) + 8);              \
      __half2 t5 = bpick(pp, 12*(g) + 10);             \
      a0 = __hfma2(t0, Ea, a0);                        \
      a1 = __hfma2(t1, Eb, a1);                        \
      a2 = __hfma2(t2, Ec, a2);                        \
      a3 = __hfma2(t3, Ed, a3);                        \
      a0 = __hfma2(t4, Ee, a0);                        \
      a1 = __hfma2(t5, Ef, a1); }

#define FV_STEP(BPF, BMK)                                            \
    { float ep = *pf; float mkn = *pmk;                              \
      float pm = wave_max63(p);          /* off critical path */     \
      float lg = LOG2F(pm);                                          \
      float c  = EXP2F(-lg - 8.0f);      /* 2^-8 / pm */             \
      k2 += lg + 8.0f;                                               \
      float pn = dppmovf<0xB1, 0xF>(p);                              \
      __half2 pp = __floats2half2_rn(p, pn);                         \
      __half2 a0 = __float2half2_rn(0.f), a1 = a0, a2 = a0, a3 = a0; \
      FVG(0, E0,  E1,  E2,  E3,  E4,  E5)                            \
      FVG(1, E6,  E7,  E8,  E9,  E10, E11)                           \
      FVG(2, E12, E13, E14, E15, E16, E17)                           \
      FVG(3, E18, E19, E20, E21, E22, E23)                           \
      a0 = __hadd2(a0, a1); a2 = __hadd2(a2, a3); a0 = __hadd2(a0, a2); \
      float accF  = __low2float(a0) + __high2float(a0);              \
      float expem = EXP2F(e1 * L2E);                                 \
      float t  = accF * expem * c;                                   \
      float pc = p * c;                                              \
      p = fminf(fmaf(mk, t - pc, pc), 1024.0f);                      \
      e1 = e2; e2 = e3; e3 = ep; mk = mkn;                           \
      if (BPF) pf += estep;                                          \
      if (BMK) pmk += B_DIM; }

    for (int s = 1; s <= 507; ++s) FV_STEP(true, true)
    FV_STEP(false, true)                   // s = 508
    FV_STEP(false, true)                   // s = 509
    FV_STEP(false, false)                  // s = 510
    FV_STEP(false, false)                  // s = 511

    float q = p * EXP2F(stopT[ri] * L2E);
    q = (i < T_DIM) ? q : 0.f;             // zero clone lanes
    float Sq = wave_sum63(q);
    float alpha = LN2 * (k2 + LOG2F(Sq));
    if (i == 0) out[1 + B_DIM + b] = alpha;
  } else {
    // ---- viterbi chain (max-plus), stale-max rebase every 8 steps ----
#define DECL_T(n) __half2 T##n = __floats2half2_rn( \
      trans[ri * T_DIM + 2*(n)], trans[ri * T_DIM + 2*(n) + 1]);
    DECL_T(0)  DECL_T(1)  DECL_T(2)  DECL_T(3)  DECL_T(4)  DECL_T(5)
    DECL_T(6)  DECL_T(7)  DECL_T(8)  DECL_T(9)  DECL_T(10) DECL_T(11)
    DECL_T(12) DECL_T(13) DECL_T(14) DECL_T(15) DECL_T(16) DECL_T(17)
    DECL_T(18) DECL_T(19) DECL_T(20) DECL_T(21) DECL_T(22) DECL_T(23)

    float v = startT[ri] + emb[0];
    const __half2 NEGI = __floats2half2_rn(-60000.f, -60000.f);
    float m_ref = wave_max63(v);

#define VVG(g, Ta, Tb, Tc, Td, Te, Tf)                 \
    { __half2 t0 = bpick(vp, 12*(g) + 0);              \
      __half2 t1 = bpick(vp, 12*(g) + 2);              \
      __half2 t2 = bpick(vp, 12*(g) + 4);              \
      __half2 t3 = bpick(vp, 12*(g) + 6);              \
      __half2 t4 = bpick(vp, 12*(g) + 8);              \
      __half2 t5 = bpick(vp, 12*(g) + 10);             \
      m0 = hmax2(m0, __hadd2(t0, Ta));                 \
      m1 = hmax2(m1, __hadd2(t1, Tb));                 \
      m2 = hmax2(m2, __hadd2(t2, Tc));                 \
      m3 = hmax2(m3, __hadd2(t3, Td));                 \
      m0 = hmax2(m0, __hadd2(t4, Te));                 \
      m1 = hmax2(m1, __hadd2(t5, Tf)); }

#define VV_STEP(DOTREE, BPF, BMK)                                    \
    { float ep = *pf; float mkn = *pmk;                              \
      if (DOTREE) m_ref = wave_max63(v);                             \
      float vr  = v - m_ref;                                         \
      float vn_ = dppmovf<0xB1, 0xF>(vr);                            \
      __half2 vp = __floats2half2_rn(vr, vn_);                       \
      __half2 m0 = NEGI, m1 = NEGI, m2 = NEGI, m3 = NEGI;            \
      VVG(0, T0,  T1,  T2,  T3,  T4,  T5)                            \
      VVG(1, T6,  T7,  T8,  T9,  T10, T11)                           \
      VVG(2, T12, T13, T14, T15, T16, T17)                           \
      VVG(3, T18, T19, T20, T21, T22, T23)                           \
      m0 = hmax2(hmax2(m0, m1), hmax2(m2, m3));                      \
      float mx = fmaxf(__low2float(m0), __high2float(m0));           \
      float vnew = e1 + m_ref + mx;                                  \
      v = fmaf(mk, vnew - v, v);                                     \
      e1 = e2; e2 = e3; e3 = ep; mk = mkn;                           \
      if (BPF) pf += estep;                                          \
      if (BMK) pmk += B_DIM; }

    // s = 1..7 (no tree; m_ref from init)
    for (int s = 1; s <= 7; ++s) VV_STEP(false, true, true)
    // s = 8..503 : 62 groups of 8, tree at group head (s % 8 == 0)
    for (int g = 0; g < 62; ++g) {
      VV_STEP(true,  true, true)
      for (int u = 0; u < 7; ++u) VV_STEP(false, true, true)
    }
    VV_STEP(true,  true, true)             // s = 504 (tree)
    for (int s = 505; s <= 507; ++s) VV_STEP(false, true, true)
    VV_STEP(false, false, true)            // s = 508
    VV_STEP(false, false, true)            // s = 509
    VV_STEP(false, false, false)           // s = 510
    VV_STEP(false, false, false)           // s = 511

    float best = wave_max63(v + stopT[ri]);
    if (i == 0) out[1 + 2 * B_DIM + b] = best;
  }
}

// ---- loss = mean(alpha - real) ----
__global__ __launch_bounds__(256)
void crf_loss(float* __restrict__ out)
{
  __shared__ float red[256];
  int t = threadIdx.x;
  float a = 0.f;
  for (int b = t; b < B_DIM; b += 256)
    a += out[1 + B_DIM + b] - out[1 + b];
  red[t] = a;
  __syncthreads();
  for (int w = 128; w > 0; w >>= 1) {
    if (t < w) red[t] += red[t + w];
    __syncthreads();
  }
  if (t == 0) out[0] = red[0] * (1.0f / B_DIM);
}

extern "C" void kernel_launch(void* const* d_in, const int* in_sizes, int n_in,
                              void* d_out, int out_size, void* d_ws, size_t ws_size,
                              hipStream_t stream) {
  (void)in_sizes; (void)n_in; (void)d_ws; (void)ws_size; (void)out_size;
  const float* em     = (const float*)d_in[0];
  const int*   tags   = (const int*)d_in[1];
  const float* mask   = (const float*)d_in[2];
  const float* trans  = (const float*)d_in[3];
  const float* startT = (const float*)d_in[4];
  const float* stopT  = (const float*)d_in[5];
  float* out = (float*)d_out;

  hipLaunchKernelGGL(crf_fused, dim3(3 * B_DIM), dim3(64), 0, stream,
                     em, tags, mask, trans, startT, stopT, out);
  hipLaunchKernelGGL(crf_loss, dim3(1), dim3(256), 0, stream, out);
}

// Round 15
// 211.119 us; speedup vs baseline: 1.0890x; 1.0615x over previous
//
#include <hip/hip_runtime.h>
#include <hip/hip_fp16.h>

#define S_LEN 512
#define B_DIM 1024
#define T_DIM 48
#define L2E 1.4426950408889634f
#define LN2 0.6931471805599453f

// v_exp_f32 computes 2^x ; v_log_f32 computes log2(x)
#define EXP2F(x) __builtin_amdgcn_exp2f(x)
#define LOG2F(x) __builtin_amdgcn_logf(x)

typedef _Float16 h2v __attribute__((ext_vector_type(2)));

// packed f16 max (ROCm 7.2 lacks __hmax2)
__device__ __forceinline__ __half2 hmax2(__half2 a, __half2 b) {
  h2v r = __builtin_elementwise_max(__builtin_bit_cast(h2v, a),
                                    __builtin_bit_cast(h2v, b));
  return __builtin_bit_cast(__half2, r);
}

// broadcast the 32-bit pair held by `lane` to all lanes (readlane -> SGPR)
__device__ __forceinline__ __half2 bpick(__half2 src, int lane) {
  int s = __builtin_amdgcn_readlane(__builtin_bit_cast(int, src), lane);
  return __builtin_bit_cast(__half2, s);
}

// ---- DPP wave-64 reduction helpers (full result valid in lane 63) ----
template <int CTRL, int RMASK>
__device__ __forceinline__ float dppmovf(float v) {
  return __int_as_float(__builtin_amdgcn_update_dpp(
      __float_as_int(v), __float_as_int(v), CTRL, RMASK, 0xF, false));
}
template <int CTRL, int RMASK>
__device__ __forceinline__ float dppmaxf(float m) {
  return fmaxf(m, dppmovf<CTRL, RMASK>(m));
}
template <int CTRL, int RMASK>
__device__ __forceinline__ float dppaddf(float m) {
  return m + dppmovf<CTRL, RMASK>(m);
}

__device__ __forceinline__ float wave_max63(float m) {
  m = dppmaxf<0xB1, 0xF>(m);   // xor 1
  m = dppmaxf<0x4E, 0xF>(m);   // xor 2
  m = dppmaxf<0x141, 0xF>(m);  // xor 4
  m = dppmaxf<0x140, 0xF>(m);  // xor 8
  m = dppmaxf<0x142, 0xA>(m);  // row_bcast15
  m = dppmaxf<0x143, 0xC>(m);  // row_bcast31 ; lane63 = full max
  return __int_as_float(__builtin_amdgcn_readlane(__float_as_int(m), 63));
}
__device__ __forceinline__ float wave_sum63(float m) {
  m = dppaddf<0xB1, 0xF>(m);
  m = dppaddf<0x4E, 0xF>(m);
  m = dppaddf<0x141, 0xF>(m);
  m = dppaddf<0x140, 0xF>(m);
  m = dppaddf<0x142, 0xA>(m);
  m = dppaddf<0x143, 0xC>(m);
  return __int_as_float(__builtin_amdgcn_readlane(__float_as_int(m), 63));
}

// Fused kernel, 64 threads/block:
//   blocks [0, 1024)      : forward (LSE) chains, exp-domain state
//   blocks [1024, 2048)   : viterbi (max) chains, stale-max-8 rebase
//   blocks [2048, 3072)   : real-path gather score (launched last; short)
// Key fixes this round: (1) in-loop asm pin of the 24 E/T constant regs
// (r12-r14 showed VGPR_Count 32-40 < static need -> compiler was
// rematerializing/spilling them every step); (2) 6-deep prefetch for both
// em and mask (mask was 1-step-prefetched, < memory latency).
__global__ __launch_bounds__(64, 2)
void crf_fused(const float* __restrict__ em, const int* __restrict__ tags,
               const float* __restrict__ mask, const float* __restrict__ trans,
               const float* __restrict__ startT, const float* __restrict__ stopT,
               float* __restrict__ out)
{
  const int blk = blockIdx.x;
  const int i   = threadIdx.x;

  if (blk >= 2 * B_DIM) {                  // ---- real-path score ----
    const int b = blk - 2 * B_DIM;
    float acc = 0.f;
#pragma unroll
    for (int k = 0; k < 8; ++k) {
      int s = 1 + i + (k << 6);
      if (s < S_LEN) {
        int   tp  = tags[(s - 1) * B_DIM + b];
        int   tc  = tags[s * B_DIM + b];
        float mkv = mask[s * B_DIM + b];
        float emt = em[((size_t)s * B_DIM + b) * T_DIM + tc];
        acc = fmaf(mkv, trans[tp * T_DIM + tc] + emt, acc);
      }
    }
    float tot = wave_sum63(acc);
    if (i == 0)
      out[1 + b] = startT[tags[b]] + stopT[tags[(S_LEN - 1) * B_DIM + b]] + tot;
    return;
  }

  const int b    = blk & (B_DIM - 1);
  const int mode = blk >> 10;              // 0 = fv, 1 = vv (same-XCD pairing)
  const int ri   = (i < T_DIM) ? i : (T_DIM - 1);

  const float* emb = em + (size_t)b * T_DIM + ri;
  const size_t estep = (size_t)B_DIM * T_DIM;
  // 6-deep shift registers: e1..e6 = em rows s..s+5, mk1..mk6 = mask rows
  float e1 = emb[1 * estep], e2 = emb[2 * estep], e3 = emb[3 * estep];
  float e4 = emb[4 * estep], e5 = emb[5 * estep], e6 = emb[6 * estep];
  float mk1 = mask[1 * B_DIM + b], mk2 = mask[2 * B_DIM + b];
  float mk3 = mask[3 * B_DIM + b], mk4 = mask[4 * B_DIM + b];
  float mk5 = mask[5 * B_DIM + b], mk6 = mask[6 * B_DIM + b];
  const float* pf  = emb + 7 * estep;        // next em row to fetch (s+6)
  const float* pmk = mask + 7 * B_DIM + b;   // next mask row to fetch (s+6)

#define SHIFT_REGS                                                   \
      e1 = e2; e2 = e3; e3 = e4; e4 = e5; e5 = e6; e6 = ep;          \
      mk1 = mk2; mk2 = mk3; mk3 = mk4; mk4 = mk5; mk5 = mk6; mk6 = mkp;

  if (mode == 0) {
    // ---- forward chain, exp-domain state: fv = LN2*k2 + ln(p) ----
#define DECL_E(n) __half2 E##n = __floats2half2_rn( \
      EXP2F(trans[ri * T_DIM + 2*(n)    ] * L2E),   \
      EXP2F(trans[ri * T_DIM + 2*(n) + 1] * L2E));
    DECL_E(0)  DECL_E(1)  DECL_E(2)  DECL_E(3)  DECL_E(4)  DECL_E(5)
    DECL_E(6)  DECL_E(7)  DECL_E(8)  DECL_E(9)  DECL_E(10) DECL_E(11)
    DECL_E(12) DECL_E(13) DECL_E(14) DECL_E(15) DECL_E(16) DECL_E(17)
    DECL_E(18) DECL_E(19) DECL_E(20) DECL_E(21) DECL_E(22) DECL_E(23)

#define PIN_E asm("" : "+v"(E0), "+v"(E1), "+v"(E2), "+v"(E3),       \
      "+v"(E4), "+v"(E5), "+v"(E6), "+v"(E7), "+v"(E8), "+v"(E9),    \
      "+v"(E10), "+v"(E11), "+v"(E12), "+v"(E13), "+v"(E14),         \
      "+v"(E15), "+v"(E16), "+v"(E17), "+v"(E18), "+v"(E19),         \
      "+v"(E20), "+v"(E21), "+v"(E22), "+v"(E23));

    float p  = EXP2F((startT[ri] + emb[0]) * L2E);   // |fv0| <= ~9, f32 safe
    float k2 = 0.f;

#define FVG(g, Ea, Eb, Ec, Ed, Ee, Ef)                 \
    { __half2 t0 = bpick(pp, 12*(g) + 0);              \
      __half2 t1 = bpick(pp, 12*(g) + 2);              \
      __half2 t2 = bpick(pp, 12*(g) + 4);              \
      __half2 t3 = bpick(pp, 12*(g) + 6);              \
      __half2 t4 = bpick(pp, 12*(g) + 8);              \
      __half2 t5 = bpick(pp, 12*(g) + 10);             \
      a0 = __hfma2(t0, Ea, a0);                        \
      a1 = __hfma2(t1, Eb, a1);                        \
      a2 = __hfma2(t2, Ec, a2);                        \
      a3 = __hfma2(t3, Ed, a3);                        \
      a0 = __hfma2(t4, Ee, a0);                        \
      a1 = __hfma2(t5, Ef, a1); }

#define FV_STEP(LOAD)                                                \
    { float ep, mkp;                                                 \
      if (LOAD) { ep = *pf; pf += estep; mkp = *pmk; pmk += B_DIM; } \
      else      { ep = e6; mkp = mk6; }                              \
      PIN_E                                                          \
      float pm = wave_max63(p);          /* off critical path */     \
      float lg = LOG2F(pm);                                          \
      float c  = EXP2F(-lg - 8.0f);      /* 2^-8 / pm */             \
      k2 += lg + 8.0f;                                               \
      float pn = dppmovf<0xB1, 0xF>(p);                              \
      __half2 pp = __floats2half2_rn(p, pn);                         \
      __half2 a0 = __float2half2_rn(0.f), a1 = a0, a2 = a0, a3 = a0; \
      FVG(0, E0,  E1,  E2,  E3,  E4,  E5)                            \
      FVG(1, E6,  E7,  E8,  E9,  E10, E11)                           \
      FVG(2, E12, E13, E14, E15, E16, E17)                           \
      FVG(3, E18, E19, E20, E21, E22, E23)                           \
      a0 = __hadd2(a0, a1); a2 = __hadd2(a2, a3); a0 = __hadd2(a0, a2); \
      float accF  = __low2float(a0) + __high2float(a0);              \
      float expem = EXP2F(e1 * L2E);                                 \
      float t  = accF * expem * c;                                   \
      float pc = p * c;                                              \
      p = fminf(fmaf(mk1, t - pc, pc), 1024.0f);                     \
      SHIFT_REGS }

#pragma unroll 6
    for (int s = 1; s <= 504; ++s) FV_STEP(true)
    FV_STEP(true)                          // s = 505 (loads row 511)
    FV_STEP(false) FV_STEP(false) FV_STEP(false)   // s = 506..508
    FV_STEP(false) FV_STEP(false) FV_STEP(false)   // s = 509..511

    float q = p * EXP2F(stopT[ri] * L2E);
    q = (i < T_DIM) ? q : 0.f;             // zero clone lanes
    float Sq = wave_sum63(q);
    float alpha = LN2 * (k2 + LOG2F(Sq));
    if (i == 0) out[1 + B_DIM + b] = alpha;
  } else {
    // ---- viterbi chain (max-plus), stale-max rebase every 8 steps ----
#define DECL_T(n) __half2 T##n = __floats2half2_rn( \
      trans[ri * T_DIM + 2*(n)], trans[ri * T_DIM + 2*(n) + 1]);
    DECL_T(0)  DECL_T(1)  DECL_T(2)  DECL_T(3)  DECL_T(4)  DECL_T(5)
    DECL_T(6)  DECL_T(7)  DECL_T(8)  DECL_T(9)  DECL_T(10) DECL_T(11)
    DECL_T(12) DECL_T(13) DECL_T(14) DECL_T(15) DECL_T(16) DECL_T(17)
    DECL_T(18) DECL_T(19) DECL_T(20) DECL_T(21) DECL_T(22) DECL_T(23)

#define PIN_T asm("" : "+v"(T0), "+v"(T1), "+v"(T2), "+v"(T3),       \
      "+v"(T4), "+v"(T5), "+v"(T6), "+v"(T7), "+v"(T8), "+v"(T9),    \
      "+v"(T10), "+v"(T11), "+v"(T12), "+v"(T13), "+v"(T14),         \
      "+v"(T15), "+v"(T16), "+v"(T17), "+v"(T18), "+v"(T19),         \
      "+v"(T20), "+v"(T21), "+v"(T22), "+v"(T23));

    float v = startT[ri] + emb[0];
    const __half2 NEGI = __floats2half2_rn(-60000.f, -60000.f);
    float m_ref = wave_max63(v);

#define VVG(g, Ta, Tb, Tc, Td, Te, Tf)                 \
    { __half2 t0 = bpick(vp, 12*(g) + 0);              \
      __half2 t1 = bpick(vp, 12*(g) + 2);              \
      __half2 t2 = bpick(vp, 12*(g) + 4);              \
      __half2 t3 = bpick(vp, 12*(g) + 6);              \
      __half2 t4 = bpick(vp, 12*(g) + 8);              \
      __half2 t5 = bpick(vp, 12*(g) + 10);             \
      m0 = hmax2(m0, __hadd2(t0, Ta));                 \
      m1 = hmax2(m1, __hadd2(t1, Tb));                 \
      m2 = hmax2(m2, __hadd2(t2, Tc));                 \
      m3 = hmax2(m3, __hadd2(t3, Td));                 \
      m0 = hmax2(m0, __hadd2(t4, Te));                 \
      m1 = hmax2(m1, __hadd2(t5, Tf)); }

#define VV_STEP(LOAD, DOTREE)                                        \
    { float ep, mkp;                                                 \
      if (LOAD) { ep = *pf; pf += estep; mkp = *pmk; pmk += B_DIM; } \
      else      { ep = e6; mkp = mk6; }                              \
      PIN_T                                                          \
      if (DOTREE) m_ref = wave_max63(v);                             \
      float vr  = v - m_ref;                                         \
      float vn_ = dppmovf<0xB1, 0xF>(vr);                            \
      __half2 vp = __floats2half2_rn(vr, vn_);                       \
      __half2 m0 = NEGI, m1 = NEGI, m2 = NEGI, m3 = NEGI;            \
      VVG(0, T0,  T1,  T2,  T3,  T4,  T5)                            \
      VVG(1, T6,  T7,  T8,  T9,  T10, T11)                           \
      VVG(2, T12, T13, T14, T15, T16, T17)                           \
      VVG(3, T18, T19, T20, T21, T22, T23)                           \
      m0 = hmax2(hmax2(m0, m1), hmax2(m2, m3));                      \
      float mx = fmaxf(__low2float(m0), __high2float(m0));           \
      float vnew = e1 + m_ref + mx;                                  \
      v = fmaf(mk1, vnew - v, v);                                    \
      SHIFT_REGS }

#pragma unroll 8
    for (int s = 1; s <= 504; ++s) VV_STEP(true, ((s & 7) == 0))
    VV_STEP(true, false)                   // s = 505 (loads row 511)
    VV_STEP(false, false) VV_STEP(false, false) VV_STEP(false, false)
    VV_STEP(false, false) VV_STEP(false, false) VV_STEP(false, false)

    float best = wave_max63(v + stopT[ri]);
    if (i == 0) out[1 + 2 * B_DIM + b] = best;
  }
}

// ---- loss = mean(alpha - real) ----
__global__ __launch_bounds__(256)
void crf_loss(float* __restrict__ out)
{
  __shared__ float red[256];
  int t = threadIdx.x;
  float a = 0.f;
  for (int b = t; b < B_DIM; b += 256)
    a += out[1 + B_DIM + b] - out[1 + b];
  red[t] = a;
  __syncthreads();
  for (int w = 128; w > 0; w >>= 1) {
    if (t < w) red[t] += red[t + w];
    __syncthreads();
  }
  if (t == 0) out[0] = red[0] * (1.0f / B_DIM);
}

extern "C" void kernel_launch(void* const* d_in, const int* in_sizes, int n_in,
                              void* d_out, int out_size, void* d_ws, size_t ws_size,
                              hipStream_t stream) {
  (void)in_sizes; (void)n_in; (void)d_ws; (void)ws_size; (void)out_size;
  const float* em     = (const float*)d_in[0];
  const int*   tags   = (const int*)d_in[1];
  const float* mask   = (const float*)d_in[2];
  const float* trans  = (const float*)d_in[3];
  const float* startT = (const float*)d_in[4];
  const float* stopT  = (const float*)d_in[5];
  float* out = (float*)d_out;

  hipLaunchKernelGGL(crf_fused, dim3(3 * B_DIM), dim3(64), 0, stream,
                     em, tags, mask, trans, startT, stopT, out);
  hipLaunchKernelGGL(crf_loss, dim3(1), dim3(256), 0, stream, out);
}

// Round 16
// 201.534 us; speedup vs baseline: 1.1408x; 1.0476x over previous
//
#include <hip/hip_runtime.h>
#include <hip/hip_fp16.h>

#define S_LEN 512
#define B_DIM 1024
#define T_DIM 48
#define L2E 1.4426950408889634f
#define LN2 0.6931471805599453f

// v_exp_f32 computes 2^x ; v_log_f32 computes log2(x)
#define EXP2F(x) __builtin_amdgcn_exp2f(x)
#define LOG2F(x) __builtin_amdgcn_logf(x)

typedef _Float16 h2v __attribute__((ext_vector_type(2)));

// packed f16 max (ROCm 7.2 lacks __hmax2)
__device__ __forceinline__ __half2 hmax2(__half2 a, __half2 b) {
  h2v r = __builtin_elementwise_max(__builtin_bit_cast(h2v, a),
                                    __builtin_bit_cast(h2v, b));
  return __builtin_bit_cast(__half2, r);
}

// broadcast the 32-bit pair held by `lane` to all lanes (readlane -> SGPR)
__device__ __forceinline__ __half2 bpick(__half2 src, int lane) {
  int s = __builtin_amdgcn_readlane(__builtin_bit_cast(int, src), lane);
  return __builtin_bit_cast(__half2, s);
}

// ---- DPP wave-64 reduction helpers (full result valid in lane 63) ----
template <int CTRL, int RMASK>
__device__ __forceinline__ float dppmovf(float v) {
  return __int_as_float(__builtin_amdgcn_update_dpp(
      __float_as_int(v), __float_as_int(v), CTRL, RMASK, 0xF, false));
}
template <int CTRL, int RMASK>
__device__ __forceinline__ float dppmaxf(float m) {
  return fmaxf(m, dppmovf<CTRL, RMASK>(m));
}
template <int CTRL, int RMASK>
__device__ __forceinline__ float dppaddf(float m) {
  return m + dppmovf<CTRL, RMASK>(m);
}

__device__ __forceinline__ float wave_max63(float m) {
  m = dppmaxf<0xB1, 0xF>(m);   // xor 1
  m = dppmaxf<0x4E, 0xF>(m);   // xor 2
  m = dppmaxf<0x141, 0xF>(m);  // xor 4
  m = dppmaxf<0x140, 0xF>(m);  // xor 8
  m = dppmaxf<0x142, 0xA>(m);  // row_bcast15
  m = dppmaxf<0x143, 0xC>(m);  // row_bcast31 ; lane63 = full max
  return __int_as_float(__builtin_amdgcn_readlane(__float_as_int(m), 63));
}
__device__ __forceinline__ float wave_sum63(float m) {
  m = dppaddf<0xB1, 0xF>(m);
  m = dppaddf<0x4E, 0xF>(m);
  m = dppaddf<0x141, 0xF>(m);
  m = dppaddf<0x140, 0xF>(m);
  m = dppaddf<0x142, 0xA>(m);
  m = dppaddf<0x143, 0xC>(m);
  return __int_as_float(__builtin_amdgcn_readlane(__float_as_int(m), 63));
}

// One block = 192 threads = 3 waves, ALL FOR THE SAME batch b:
//   wave 0: forward (LSE) chain, exp-domain state
//   wave 1: viterbi (max) chain, stale-max-8 rebase
//   wave 2: real-path gather (finishes in ~8us, then frees the SIMD slot;
//           its ahead-of-scan em reads prefetch rows into the CU's L1)
// Same-CU placement makes fv/vv share every em/mask line via L1 (r15 showed
// 204MB FETCH = em fetched twice from HBM when pairing was by-grid-order).
// E/T constants live in 24 named VGPRs, pinned in-loop (r15: VGPR 36->44).
__global__ __launch_bounds__(192, 3)
void crf_fused(const float* __restrict__ em, const int* __restrict__ tags,
               const float* __restrict__ mask, const float* __restrict__ trans,
               const float* __restrict__ startT, const float* __restrict__ stopT,
               float* __restrict__ out)
{
  const int b    = blockIdx.x;
  const int wave = threadIdx.x >> 6;
  const int i    = threadIdx.x & 63;

  if (wave == 2) {                         // ---- real-path score ----
    float acc = 0.f;
#pragma unroll
    for (int k = 0; k < 8; ++k) {
      int s = 1 + i + (k << 6);
      if (s < S_LEN) {
        int   tp  = tags[(s - 1) * B_DIM + b];
        int   tc  = tags[s * B_DIM + b];
        float mkv = mask[s * B_DIM + b];
        float emt = em[((size_t)s * B_DIM + b) * T_DIM + tc];
        acc = fmaf(mkv, trans[tp * T_DIM + tc] + emt, acc);
      }
    }
    float tot = wave_sum63(acc);
    if (i == 0)
      out[1 + b] = startT[tags[b]] + stopT[tags[(S_LEN - 1) * B_DIM + b]] + tot;
    return;
  }

  const int ri = (i < T_DIM) ? i : (T_DIM - 1);

  const float* emb = em + (size_t)b * T_DIM + ri;
  const size_t estep = (size_t)B_DIM * T_DIM;
  // 6-deep shift registers: e1..e6 = em rows s..s+5, mk1..mk6 = mask rows
  float e1 = emb[1 * estep], e2 = emb[2 * estep], e3 = emb[3 * estep];
  float e4 = emb[4 * estep], e5 = emb[5 * estep], e6 = emb[6 * estep];
  float mk1 = mask[1 * B_DIM + b], mk2 = mask[2 * B_DIM + b];
  float mk3 = mask[3 * B_DIM + b], mk4 = mask[4 * B_DIM + b];
  float mk5 = mask[5 * B_DIM + b], mk6 = mask[6 * B_DIM + b];
  const float* pf  = emb + 7 * estep;        // next em row to fetch (s+6)
  const float* pmk = mask + 7 * B_DIM + b;   // next mask row to fetch (s+6)

#define SHIFT_REGS                                                   \
      e1 = e2; e2 = e3; e3 = e4; e4 = e5; e5 = e6; e6 = ep;          \
      mk1 = mk2; mk2 = mk3; mk3 = mk4; mk4 = mk5; mk5 = mk6; mk6 = mkp;

  if (wave == 0) {
    // ---- forward chain, exp-domain state: fv = LN2*k2 + ln(p) ----
#define DECL_E(n) __half2 E##n = __floats2half2_rn( \
      EXP2F(trans[ri * T_DIM + 2*(n)    ] * L2E),   \
      EXP2F(trans[ri * T_DIM + 2*(n) + 1] * L2E));
    DECL_E(0)  DECL_E(1)  DECL_E(2)  DECL_E(3)  DECL_E(4)  DECL_E(5)
    DECL_E(6)  DECL_E(7)  DECL_E(8)  DECL_E(9)  DECL_E(10) DECL_E(11)
    DECL_E(12) DECL_E(13) DECL_E(14) DECL_E(15) DECL_E(16) DECL_E(17)
    DECL_E(18) DECL_E(19) DECL_E(20) DECL_E(21) DECL_E(22) DECL_E(23)

#define PIN_E asm("" : "+v"(E0), "+v"(E1), "+v"(E2), "+v"(E3),       \
      "+v"(E4), "+v"(E5), "+v"(E6), "+v"(E7), "+v"(E8), "+v"(E9),    \
      "+v"(E10), "+v"(E11), "+v"(E12), "+v"(E13), "+v"(E14),         \
      "+v"(E15), "+v"(E16), "+v"(E17), "+v"(E18), "+v"(E19),         \
      "+v"(E20), "+v"(E21), "+v"(E22), "+v"(E23));

    float p  = EXP2F((startT[ri] + emb[0]) * L2E);   // |fv0| <= ~9, f32 safe
    float k2 = 0.f;

#define FVG(g, Ea, Eb, Ec, Ed, Ee, Ef)                 \
    { __half2 t0 = bpick(pp, 12*(g) + 0);              \
      __half2 t1 = bpick(pp, 12*(g) + 2);              \
      __half2 t2 = bpick(pp, 12*(g) + 4);              \
      __half2 t3 = bpick(pp, 12*(g) + 6);              \
      __half2 t4 = bpick(pp, 12*(g) + 8);              \
      __half2 t5 = bpick(pp, 12*(g) + 10);             \
      a0 = __hfma2(t0, Ea, a0);                        \
      a1 = __hfma2(t1, Eb, a1);                        \
      a2 = __hfma2(t2, Ec, a2);                        \
      a3 = __hfma2(t3, Ed, a3);                        \
      a0 = __hfma2(t4, Ee, a0);                        \
      a1 = __hfma2(t5, Ef, a1); }

#define FV_STEP(LOAD)                                                \
    { float ep, mkp;                                                 \
      if (LOAD) { ep = *pf; pf += estep; mkp = *pmk; pmk += B_DIM; } \
      else      { ep = e6; mkp = mk6; }                              \
      PIN_E                                                          \
      float pm = wave_max63(p);          /* off critical path */     \
      float lg = LOG2F(pm);                                          \
      float c  = EXP2F(-lg - 8.0f);      /* 2^-8 / pm */             \
      k2 += lg + 8.0f;                                               \
      float pn = dppmovf<0xB1, 0xF>(p);                              \
      __half2 pp = __floats2half2_rn(p, pn);                         \
      __half2 a0 = __float2half2_rn(0.f), a1 = a0, a2 = a0, a3 = a0; \
      FVG(0, E0,  E1,  E2,  E3,  E4,  E5)                            \
      FVG(1, E6,  E7,  E8,  E9,  E10, E11)                           \
      FVG(2, E12, E13, E14, E15, E16, E17)                           \
      FVG(3, E18, E19, E20, E21, E22, E23)                           \
      a0 = __hadd2(a0, a1); a2 = __hadd2(a2, a3); a0 = __hadd2(a0, a2); \
      float accF  = __low2float(a0) + __high2float(a0);              \
      float expem = EXP2F(e1 * L2E);                                 \
      float t  = accF * expem * c;                                   \
      float pc = p * c;                                              \
      p = fminf(fmaf(mk1, t - pc, pc), 1024.0f);                     \
      SHIFT_REGS }

#pragma unroll 6
    for (int s = 1; s <= 504; ++s) FV_STEP(true)
    FV_STEP(true)                          // s = 505 (loads row 511)
    FV_STEP(false) FV_STEP(false) FV_STEP(false)   // s = 506..508
    FV_STEP(false) FV_STEP(false) FV_STEP(false)   // s = 509..511

    float q = p * EXP2F(stopT[ri] * L2E);
    q = (i < T_DIM) ? q : 0.f;             // zero clone lanes
    float Sq = wave_sum63(q);
    float alpha = LN2 * (k2 + LOG2F(Sq));
    if (i == 0) out[1 + B_DIM + b] = alpha;
  } else {
    // ---- viterbi chain (max-plus), stale-max rebase every 8 steps ----
#define DECL_T(n) __half2 T##n = __floats2half2_rn( \
      trans[ri * T_DIM + 2*(n)], trans[ri * T_DIM + 2*(n) + 1]);
    DECL_T(0)  DECL_T(1)  DECL_T(2)  DECL_T(3)  DECL_T(4)  DECL_T(5)
    DECL_T(6)  DECL_T(7)  DECL_T(8)  DECL_T(9)  DECL_T(10) DECL_T(11)
    DECL_T(12) DECL_T(13) DECL_T(14) DECL_T(15) DECL_T(16) DECL_T(17)
    DECL_T(18) DECL_T(19) DECL_T(20) DECL_T(21) DECL_T(22) DECL_T(23)

#define PIN_T asm("" : "+v"(T0), "+v"(T1), "+v"(T2), "+v"(T3),       \
      "+v"(T4), "+v"(T5), "+v"(T6), "+v"(T7), "+v"(T8), "+v"(T9),    \
      "+v"(T10), "+v"(T11), "+v"(T12), "+v"(T13), "+v"(T14),         \
      "+v"(T15), "+v"(T16), "+v"(T17), "+v"(T18), "+v"(T19),         \
      "+v"(T20), "+v"(T21), "+v"(T22), "+v"(T23));

    float v = startT[ri] + emb[0];
    const __half2 NEGI = __floats2half2_rn(-60000.f, -60000.f);
    float m_ref = wave_max63(v);

#define VVG(g, Ta, Tb, Tc, Td, Te, Tf)                 \
    { __half2 t0 = bpick(vp, 12*(g) + 0);              \
      __half2 t1 = bpick(vp, 12*(g) + 2);              \
      __half2 t2 = bpick(vp, 12*(g) + 4);              \
      __half2 t3 = bpick(vp, 12*(g) + 6);              \
      __half2 t4 = bpick(vp, 12*(g) + 8);              \
      __half2 t5 = bpick(vp, 12*(g) + 10);             \
      m0 = hmax2(m0, __hadd2(t0, Ta));                 \
      m1 = hmax2(m1, __hadd2(t1, Tb));                 \
      m2 = hmax2(m2, __hadd2(t2, Tc));                 \
      m3 = hmax2(m3, __hadd2(t3, Td));                 \
      m0 = hmax2(m0, __hadd2(t4, Te));                 \
      m1 = hmax2(m1, __hadd2(t5, Tf)); }

#define VV_STEP(LOAD, DOTREE)                                        \
    { float ep, mkp;                                                 \
      if (LOAD) { ep = *pf; pf += estep; mkp = *pmk; pmk += B_DIM; } \
      else      { ep = e6; mkp = mk6; }                              \
      PIN_T                                                          \
      if (DOTREE) m_ref = wave_max63(v);                             \
      float vr  = v - m_ref;                                         \
      float vn_ = dppmovf<0xB1, 0xF>(vr);                            \
      __half2 vp = __floats2half2_rn(vr, vn_);                       \
      __half2 m0 = NEGI, m1 = NEGI, m2 = NEGI, m3 = NEGI;            \
      VVG(0, T0,  T1,  T2,  T3,  T4,  T5)                            \
      VVG(1, T6,  T7,  T8,  T9,  T10, T11)                           \
      VVG(2, T12, T13, T14, T15, T16, T17)                           \
      VVG(3, T18, T19, T20, T21, T22, T23)                           \
      m0 = hmax2(hmax2(m0, m1), hmax2(m2, m3));                      \
      float mx = fmaxf(__low2float(m0), __high2float(m0));           \
      float vnew = e1 + m_ref + mx;                                  \
      v = fmaf(mk1, vnew - v, v);                                    \
      SHIFT_REGS }

#pragma unroll 8
    for (int s = 1; s <= 504; ++s) VV_STEP(true, ((s & 7) == 0))
    VV_STEP(true, false)                   // s = 505 (loads row 511)
    VV_STEP(false, false) VV_STEP(false, false) VV_STEP(false, false)
    VV_STEP(false, false) VV_STEP(false, false) VV_STEP(false, false)

    float best = wave_max63(v + stopT[ri]);
    if (i == 0) out[1 + 2 * B_DIM + b] = best;
  }
}

// ---- loss = mean(alpha - real) ----
__global__ __launch_bounds__(256)
void crf_loss(float* __restrict__ out)
{
  __shared__ float red[256];
  int t = threadIdx.x;
  float a = 0.f;
  for (int b = t; b < B_DIM; b += 256)
    a += out[1 + B_DIM + b] - out[1 + b];
  red[t] = a;
  __syncthreads();
  for (int w = 128; w > 0; w >>= 1) {
    if (t < w) red[t] += red[t + w];
    __syncthreads();
  }
  if (t == 0) out[0] = red[0] * (1.0f / B_DIM);
}

extern "C" void kernel_launch(void* const* d_in, const int* in_sizes, int n_in,
                              void* d_out, int out_size, void* d_ws, size_t ws_size,
                              hipStream_t stream) {
  (void)in_sizes; (void)n_in; (void)d_ws; (void)ws_size; (void)out_size;
  const float* em     = (const float*)d_in[0];
  const int*   tags   = (const int*)d_in[1];
  const float* mask   = (const float*)d_in[2];
  const float* trans  = (const float*)d_in[3];
  const float* startT = (const float*)d_in[4];
  const float* stopT  = (const float*)d_in[5];
  float* out = (float*)d_out;

  hipLaunchKernelGGL(crf_fused, dim3(B_DIM), dim3(192), 0, stream,
                     em, tags, mask, trans, startT, stopT, out);
  hipLaunchKernelGGL(crf_loss, dim3(1), dim3(256), 0, stream, out);
}